// Round 7
// baseline (976.417 us; speedup 1.0000x reference)
//
#include <hip/hip_runtime.h>
#include <hip/hip_bf16.h>
#include <math.h>

#define N_NODES 50000
#define N_EDGES 500000
#define DIM     128
#define NLAYER  4
#define NEFEAT  7

static constexpr float LN_EPS    = 1e-5f;
static constexpr float ATT_SCALE = 0.17677669529663687f;  // 1/sqrt(32)

typedef short s16x8 __attribute__((ext_vector_type(8)));   // 8 bf16 (4 VGPR) MFMA A/B frag
typedef float f32x4 __attribute__((ext_vector_type(4)));   // MFMA C/D frag

static __device__ __forceinline__ float leaky(float x){ return x >= 0.f ? x : 0.01f*x; }

static __device__ __forceinline__ unsigned short f2bf(float f){
    __hip_bfloat16 b = __float2bfloat16(f);
    return *reinterpret_cast<unsigned short*>(&b);
}
static __device__ __forceinline__ float bflo(unsigned int u){ return __uint_as_float(u << 16); }
static __device__ __forceinline__ float bfhi(unsigned int u){ return __uint_as_float(u & 0xFFFF0000u); }

// ---------------- init h(bf16 only) = node_table[0] broadcast ----------------
__global__ void init_h_kernel(const float* __restrict__ node_table,
                              unsigned short* __restrict__ hb){
    int i = blockIdx.x*blockDim.x + threadIdx.x;
    if (i < N_NODES*DIM) hb[i] = f2bf(node_table[i & (DIM-1)]);
}

// ---------------- CSR build ----------------
__global__ void zero2_kernel(int* __restrict__ a, int* __restrict__ b){
    int i = blockIdx.x*blockDim.x + threadIdx.x;
    if (i < N_NODES){ a[i] = 0; b[i] = 0; }
}

__global__ void count_kernel(const int* __restrict__ dst, int* __restrict__ cnt){
    int e = blockIdx.x*blockDim.x + threadIdx.x;
    if (e < N_EDGES) atomicAdd(&cnt[dst[e]], 1);
}

__global__ void scan_kernel(const int* __restrict__ cnt, int* __restrict__ rowptr){
    __shared__ int wsum[16];
    __shared__ int runsh;
    if (threadIdx.x == 0) runsh = 0;
    __syncthreads();
    int lane = threadIdx.x & 63, wid = threadIdx.x >> 6;
    for (int base = 0; base < N_NODES; base += 1024){
        int i = base + (int)threadIdx.x;
        int vv = (i < N_NODES) ? cnt[i] : 0;
        int s = vv;
        #pragma unroll
        for (int off = 1; off < 64; off <<= 1){
            int t = __shfl_up(s, off);
            if (lane >= off) s += t;
        }
        if (lane == 63) wsum[wid] = s;
        __syncthreads();
        if (wid == 0 && lane < 16){
            int x = wsum[lane];
            #pragma unroll
            for (int off = 1; off < 16; off <<= 1){
                int t = __shfl_up(x, off);
                if (lane >= off) x += t;
            }
            wsum[lane] = x;
        }
        __syncthreads();
        int wpre = (wid == 0) ? 0 : wsum[wid-1];
        int run  = runsh;
        if (i < N_NODES) rowptr[i] = run + wpre + s - vv;   // exclusive
        __syncthreads();
        if (threadIdx.x == 0) runsh = run + wsum[15];
        __syncthreads();
    }
    if (threadIdx.x == 0) rowptr[N_NODES] = runsh;
}

__global__ void scatter_kernel(const int* __restrict__ src, const int* __restrict__ dst,
                               const float* __restrict__ edge_attr,
                               const int* __restrict__ rowptr, int* __restrict__ fill,
                               int* __restrict__ srcs, unsigned int* __restrict__ eab){
    int e = blockIdx.x*blockDim.x + threadIdx.x;
    if (e >= N_EDGES) return;
    int d   = dst[e];
    int pos = rowptr[d] + atomicAdd(&fill[d], 1);
    srcs[pos] = src[e];
    const float* a = edge_attr + (size_t)e*NEFEAT;
    uint4 u;
    u.x = (unsigned int)f2bf(a[0]) | ((unsigned int)f2bf(a[1]) << 16);
    u.y = (unsigned int)f2bf(a[2]) | ((unsigned int)f2bf(a[3]) << 16);
    u.z = (unsigned int)f2bf(a[4]) | ((unsigned int)f2bf(a[5]) << 16);
    u.w = (unsigned int)f2bf(a[6]) | (0x3F80u << 16);   // bias slot = 1.0
    *(uint4*)(eab + (size_t)pos*4) = u;
}

// ---------------- Weff[l] = [Wee@We_l ; bee@We_l + be_l]  (8 x 128), all layers ----------
__global__ void weff_all_kernel(const float* __restrict__ Wee, const float* __restrict__ bee,
                                const float* __restrict__ We, const float* __restrict__ be,
                                float* __restrict__ weff){
    int l = blockIdx.x;
    int d = threadIdx.x;  // 128 threads
    const float* We_l = We + (size_t)l*DIM*DIM;
    float* out = weff + (size_t)l*8*DIM;
    for (int c = 0; c < NEFEAT; ++c){
        float s = 0.f;
        for (int t = 0; t < DIM; ++t) s += Wee[c*DIM + t] * We_l[t*DIM + d];
        out[c*DIM + d] = s;
    }
    float s = 0.f;
    for (int t = 0; t < DIM; ++t) s += bee[t] * We_l[t*DIM + d];
    out[7*DIM + d] = s + be[l*DIM + d];
}

// ---------------- weight prep: bf16 transposed copies ----------------
__global__ void prepw_kernel(const float* __restrict__ Wq, const float* __restrict__ Wk,
                             const float* __restrict__ Wv, const float* __restrict__ Ws,
                             const float* __restrict__ W1, const float* __restrict__ W2,
                             unsigned short* __restrict__ wqkvsT,
                             unsigned short* __restrict__ w1T,
                             unsigned short* __restrict__ w2T){
    int tid = blockIdx.x*blockDim.x + threadIdx.x;
    if (tid >= NLAYER*131072) return;
    int l = tid >> 17;
    int r = tid & 131071;
    if (r < 65536){
        int n = r >> 7, k = r & 127;
        int p = n >> 7, nn = n & 127;
        const float* W = (p==0)?Wq:(p==1)?Wk:(p==2)?Wv:Ws;
        float val = W[(size_t)l*DIM*DIM + (size_t)k*DIM + nn];
        wqkvsT[(size_t)l*65536 + (size_t)n*128 + k] = f2bf(val);
    } else if (r < 98304){
        int r2 = r - 65536;
        int n = r2 >> 7, k = r2 & 127;
        float val = W1[(size_t)l*32768 + (size_t)k*256 + n];
        w1T[(size_t)l*32768 + (size_t)n*128 + k] = f2bf(val);
    } else {
        int r2 = r - 98304;
        int n = r2 >> 8, k = r2 & 255;
        float val = W2[(size_t)l*32768 + (size_t)k*128 + n];
        w2T[(size_t)l*32768 + (size_t)n*256 + k] = f2bf(val);
    }
}

// ---------------- QKVS GEMM via MFMA: [N,128]bf16 @ [128,512]bf16 ----------------
// grid (tiles, 2); 4 waves, 64 rows/tile.
// y=0: parts {q, s}  -> qs[row][col] = q | s<<16
// y=1: parts {k, v}  -> kv[row][col] = k | v<<16
__global__ __launch_bounds__(256) void qkvs_mfma_kernel(
    const unsigned short* __restrict__ hb, const unsigned short* __restrict__ wT,
    const float* __restrict__ bq, const float* __restrict__ bk,
    const float* __restrict__ bv, const float* __restrict__ bs,
    unsigned int* __restrict__ qs, unsigned int* __restrict__ kv)
{
    __shared__ char sA[64*256];   // [64][128] bf16, XOR-swizzled
    int row0 = blockIdx.x*64;
    for (int idx = threadIdx.x; idx < 1024; idx += 256){
        int row = idx >> 4, k16 = idx & 15;
        int byte = row*256 + k16*16;  byte ^= (row & 7) << 4;
        s16x8 val = {0,0,0,0,0,0,0,0};
        int grow = row0 + row;
        if (grow < N_NODES) val = *(const s16x8*)(hb + (size_t)grow*128 + k16*8);
        *(s16x8*)(sA + byte) = val;
    }
    __syncthreads();

    int w = threadIdx.x >> 6, l = threadIdx.x & 63;
    int y = blockIdx.y;
    int pb0 = y ? 128 : 0;
    int pb1 = y ? 256 : 384;

    f32x4 acc[4][4];
    #pragma unroll
    for (int rf=0;rf<4;++rf)
        #pragma unroll
        for (int cf=0;cf<4;++cf) acc[rf][cf] = (f32x4){0.f,0.f,0.f,0.f};

    s16x8 af[2][4], bf[2][4];
    #pragma unroll
    for (int rf=0;rf<4;++rf){
        int row = rf*16 + (l & 15);
        int byte = row*256 + (l >> 4)*16;  byte ^= (row & 7) << 4;
        af[0][rf] = *(const s16x8*)(sA + byte);
    }
    #pragma unroll
    for (int cf=0;cf<4;++cf){
        int nrow = ((cf < 2) ? pb0 : pb1) + (w<<5) + ((cf&1)<<4) + (l & 15);
        bf[0][cf] = *(const s16x8*)(wT + (size_t)nrow*128 + (l >> 4)*8);
    }
    #pragma unroll
    for (int kb = 0; kb < 4; ++kb){
        int cur = kb & 1, nxt = cur ^ 1;
        if (kb < 3){
            #pragma unroll
            for (int rf=0;rf<4;++rf){
                int row = rf*16 + (l & 15);
                int byte = row*256 + (kb+1)*64 + (l >> 4)*16;  byte ^= (row & 7) << 4;
                af[nxt][rf] = *(const s16x8*)(sA + byte);
            }
            #pragma unroll
            for (int cf=0;cf<4;++cf){
                int nrow = ((cf < 2) ? pb0 : pb1) + (w<<5) + ((cf&1)<<4) + (l & 15);
                bf[nxt][cf] = *(const s16x8*)(wT + (size_t)nrow*128 + (kb+1)*32 + (l >> 4)*8);
            }
        }
        #pragma unroll
        for (int rf=0;rf<4;++rf)
            #pragma unroll
            for (int cf=0;cf<4;++cf)
                acc[rf][cf] = __builtin_amdgcn_mfma_f32_16x16x32_bf16(af[cur][rf], bf[cur][cf], acc[rf][cf], 0, 0, 0);
    }

    const float* biasLo = y ? bk : bq;
    const float* biasHi = y ? bv : bs;
    unsigned int* outp  = y ? kv : qs;
    #pragma unroll
    for (int cp = 0; cp < 2; ++cp){
        int col = (w<<5) + (cp<<4) + (l & 15);
        float blo = biasLo[col], bhi = biasHi[col];
        #pragma unroll
        for (int rf=0;rf<4;++rf){
            #pragma unroll
            for (int r=0;r<4;++r){
                int row = row0 + rf*16 + ((l >> 4) << 2) + r;
                if (row < N_NODES){
                    float lo = acc[rf][cp][r]   + blo;
                    float hi = acc[rf][cp+2][r] + bhi;
                    outp[(size_t)row*128 + col] =
                        (unsigned int)f2bf(lo) | ((unsigned int)f2bf(hi) << 16);
                }
            }
        }
    }
}

// ---------------- attention + skip + LN1 fused: TWO nodes per wave -----------
// alpha = (q*scale).k[src] + qe.ea ; agg = (sum p*v + (sum p*ea)@Weff)/den
// Two independent edge streams per wave double memory-level parallelism.
__global__ __launch_bounds__(256) void attn_kernel(
    const unsigned int* __restrict__ qs, const unsigned int* __restrict__ kv,
    const float* __restrict__ weff_l, const int* __restrict__ rowptr,
    const int* __restrict__ srcs, const unsigned int* __restrict__ eab,
    const unsigned short* __restrict__ hb,
    const float* __restrict__ n1g, const float* __restrict__ n1b,
    unsigned short* __restrict__ x1b)
{
    __shared__ float wf[8][DIM];
    for (int i = threadIdx.x; i < 8*DIM; i += 256) ((float*)wf)[i] = weff_l[i];
    __syncthreads();
    int wv = threadIdx.x >> 6, lane = threadIdx.x & 63;
    int nA = blockIdx.x*8 + wv*2;
    if (nA >= N_NODES) return;
    int nB = nA + 1;
    bool hasB = (nB < N_NODES);
    int d0 = lane*2;

    uint2 qsbA = *(const uint2*)(qs + (size_t)nA*DIM + d0);
    uint2 qsbB = {0u, 0u};
    if (hasB) qsbB = *(const uint2*)(qs + (size_t)nB*DIM + d0);
    float q0A = bflo(qsbA.x)*ATT_SCALE, q1A = bflo(qsbA.y)*ATT_SCALE;
    float q0B = bflo(qsbB.x)*ATT_SCALE, q1B = bflo(qsbB.y)*ATT_SCALE;

    // qe[c] = sum_{d in head} (q*scale)_d * Weff[c][d]  (head = 16-lane group)
    float qeA[8], qeB[8];
    #pragma unroll
    for (int c = 0; c < 8; ++c){
        float2 wc = *(const float2*)&wf[c][d0];
        float pA = q0A*wc.x + q1A*wc.y;
        float pB = q0B*wc.x + q1B*wc.y;
        pA += __shfl_xor(pA, 1); pB += __shfl_xor(pB, 1);
        pA += __shfl_xor(pA, 2); pB += __shfl_xor(pB, 2);
        pA += __shfl_xor(pA, 4); pB += __shfl_xor(pB, 4);
        pA += __shfl_xor(pA, 8); pB += __shfl_xor(pB, 8);
        qeA[c] = pA; qeB[c] = pB;
    }

    int begA = rowptr[nA], degA = rowptr[nA+1] - begA;
    int begB = 0, degB = 0;
    if (hasB){ begB = rowptr[nB]; degB = rowptr[nB+1] - begB; }

    float mA = -1e30f, denA = 0.f, a0A = 0.f, a1A = 0.f;
    float pA0=0.f,pA1=0.f,pA2=0.f,pA3=0.f,pA4=0.f,pA5=0.f,pA6=0.f;
    float mB = -1e30f, denB = 0.f, a0B = 0.f, a1B = 0.f;
    float pB0=0.f,pB1=0.f,pB2=0.f,pB3=0.f,pB4=0.f,pB5=0.f,pB6=0.f;

    int degM = degA > degB ? degA : degB;
    for (int cb = 0; cb < degM; cb += 64){
        int srcvA = 0, srcvB = 0;
        if (cb + lane < degA) srcvA = srcs[begA + cb + lane];
        if (cb + lane < degB) srcvB = srcs[begB + cb + lane];
        int cA = degA - cb; if (cA > 64) cA = 64;
        int cB = degB - cb; if (cB > 64) cB = 64;
        int cM = cA > cB ? cA : cB;
        for (int j = 0; j < cM; ++j){
            uint2 kvA, kvB; uint4 euA, euB;
            bool doA = (j < cA), doB = (j < cB);     // wave-uniform
            if (doA){
                int sv = __shfl(srcvA, j);
                kvA = *(const uint2*)(kv + (size_t)sv*DIM + d0);
                euA = *(const uint4*)(eab + ((size_t)(begA + cb + j) << 2));
            }
            if (doB){
                int sv = __shfl(srcvB, j);
                kvB = *(const uint2*)(kv + (size_t)sv*DIM + d0);
                euB = *(const uint4*)(eab + ((size_t)(begB + cb + j) << 2));
            }
            if (doA){
                float e0=bflo(euA.x), e1=bfhi(euA.x), e2=bflo(euA.y), e3=bfhi(euA.y);
                float e4=bflo(euA.z), e5=bfhi(euA.z), e6=bflo(euA.w);
                float p = q0A*bflo(kvA.x) + q1A*bflo(kvA.y);
                p += __shfl_xor(p, 1); p += __shfl_xor(p, 2);
                p += __shfl_xor(p, 4); p += __shfl_xor(p, 8);
                float al = p + qeA[7] + qeA[0]*e0 + qeA[1]*e1 + qeA[2]*e2 + qeA[3]*e3
                                     + qeA[4]*e4 + qeA[5]*e5 + qeA[6]*e6;
                float nm = fmaxf(mA, al);
                float f  = __expf(mA - nm);
                float pp = __expf(al - nm);
                denA = denA*f + pp;
                a0A  = a0A*f  + pp*bfhi(kvA.x);
                a1A  = a1A*f  + pp*bfhi(kvA.y);
                pA0 = pA0*f + pp*e0;  pA1 = pA1*f + pp*e1;
                pA2 = pA2*f + pp*e2;  pA3 = pA3*f + pp*e3;
                pA4 = pA4*f + pp*e4;  pA5 = pA5*f + pp*e5;
                pA6 = pA6*f + pp*e6;
                mA = nm;
            }
            if (doB){
                float e0=bflo(euB.x), e1=bfhi(euB.x), e2=bflo(euB.y), e3=bfhi(euB.y);
                float e4=bflo(euB.z), e5=bfhi(euB.z), e6=bflo(euB.w);
                float p = q0B*bflo(kvB.x) + q1B*bflo(kvB.y);
                p += __shfl_xor(p, 1); p += __shfl_xor(p, 2);
                p += __shfl_xor(p, 4); p += __shfl_xor(p, 8);
                float al = p + qeB[7] + qeB[0]*e0 + qeB[1]*e1 + qeB[2]*e2 + qeB[3]*e3
                                     + qeB[4]*e4 + qeB[5]*e5 + qeB[6]*e6;
                float nm = fmaxf(mB, al);
                float f  = __expf(mB - nm);
                float pp = __expf(al - nm);
                denB = denB*f + pp;
                a0B  = a0B*f  + pp*bfhi(kvB.x);
                a1B  = a1B*f  + pp*bfhi(kvB.y);
                pB0 = pB0*f + pp*e0;  pB1 = pB1*f + pp*e1;
                pB2 = pB2*f + pp*e2;  pB3 = pB3*f + pp*e3;
                pB4 = pB4*f + pp*e4;  pB5 = pB5*f + pp*e5;
                pB6 = pB6*f + pp*e6;
                mB = nm;
            }
        }
    }

    float2 w0 = *(const float2*)&wf[0][d0];
    float2 w1c = *(const float2*)&wf[1][d0];
    float2 w2c = *(const float2*)&wf[2][d0];
    float2 w3c = *(const float2*)&wf[3][d0];
    float2 w4c = *(const float2*)&wf[4][d0];
    float2 w5c = *(const float2*)&wf[5][d0];
    float2 w6c = *(const float2*)&wf[6][d0];
    float2 w7c = *(const float2*)&wf[7][d0];
    float gg0 = n1g[d0], gg1 = n1g[d0+1], bb0 = n1b[d0], bb1 = n1b[d0+1];

    // ---- epilogue A
    {
        float inv = (denA > 0.f) ? 1.f/denA : 0.f;
        float ev0 = pA0*w0.x + pA1*w1c.x + pA2*w2c.x + pA3*w3c.x
                  + pA4*w4c.x + pA5*w5c.x + pA6*w6c.x + denA*w7c.x;
        float ev1 = pA0*w0.y + pA1*w1c.y + pA2*w2c.y + pA3*w3c.y
                  + pA4*w4c.y + pA5*w5c.y + pA6*w6c.y + denA*w7c.y;
        unsigned int hu = *(const unsigned int*)(hb + (size_t)nA*DIM + d0);
        float t0 = bflo(hu) + (a0A + ev0)*inv + bfhi(qsbA.x);
        float t1 = bfhi(hu) + (a1A + ev1)*inv + bfhi(qsbA.y);
        float sum = t0 + t1, ss = t0*t0 + t1*t1;
        #pragma unroll
        for (int off = 1; off < 64; off <<= 1){
            sum += __shfl_xor(sum, off);
            ss  += __shfl_xor(ss,  off);
        }
        float mu = sum * (1.f/DIM);
        float rstd = rsqrtf(ss*(1.f/DIM) - mu*mu + LN_EPS);
        float o0 = (t0-mu)*rstd*gg0 + bb0;
        float o1 = (t1-mu)*rstd*gg1 + bb1;
        unsigned int pk = (unsigned int)f2bf(o0) | ((unsigned int)f2bf(o1) << 16);
        *(unsigned int*)(x1b + (size_t)nA*DIM + d0) = pk;
    }
    // ---- epilogue B
    if (hasB){
        float inv = (denB > 0.f) ? 1.f/denB : 0.f;
        float ev0 = pB0*w0.x + pB1*w1c.x + pB2*w2c.x + pB3*w3c.x
                  + pB4*w4c.x + pB5*w5c.x + pB6*w6c.x + denB*w7c.x;
        float ev1 = pB0*w0.y + pB1*w1c.y + pB2*w2c.y + pB3*w3c.y
                  + pB4*w4c.y + pB5*w5c.y + pB6*w6c.y + denB*w7c.y;
        unsigned int hu = *(const unsigned int*)(hb + (size_t)nB*DIM + d0);
        float t0 = bflo(hu) + (a0B + ev0)*inv + bfhi(qsbB.x);
        float t1 = bfhi(hu) + (a1B + ev1)*inv + bfhi(qsbB.y);
        float sum = t0 + t1, ss = t0*t0 + t1*t1;
        #pragma unroll
        for (int off = 1; off < 64; off <<= 1){
            sum += __shfl_xor(sum, off);
            ss  += __shfl_xor(ss,  off);
        }
        float mu = sum * (1.f/DIM);
        float rstd = rsqrtf(ss*(1.f/DIM) - mu*mu + LN_EPS);
        float o0 = (t0-mu)*rstd*gg0 + bb0;
        float o1 = (t1-mu)*rstd*gg1 + bb1;
        unsigned int pk = (unsigned int)f2bf(o0) | ((unsigned int)f2bf(o1) << 16);
        *(unsigned int*)(x1b + (size_t)nB*DIM + d0) = pk;
    }
}

// ---------------- FFN via MFMA + LN2 + LN3 + act + residual ----------------
// Residual h kept in bf16 between layers; last layer writes f32 to d_out.
__global__ __launch_bounds__(256) void ffn_mfma_kernel(
    const unsigned short* __restrict__ x1b,
    const unsigned short* __restrict__ hbin,
    const unsigned short* __restrict__ w1T, const float* __restrict__ b1,
    const unsigned short* __restrict__ w2T, const float* __restrict__ b2,
    const float* __restrict__ n2g, const float* __restrict__ n2b,
    const float* __restrict__ lng, const float* __restrict__ lnb,
    int last, float* __restrict__ h, unsigned short* __restrict__ hb)
{
    __shared__ char smem[49152];
    char* sA   = smem;            // [64][128] bf16 swz (x1 tile)
    char* sMid = smem + 16384;    // [64][256] bf16 swz (mid) -> later ffout [64][128] f32 swz
    int row0 = blockIdx.x*64;
    for (int idx = threadIdx.x; idx < 1024; idx += 256){
        int row = idx >> 4, k16 = idx & 15;
        int byte = row*256 + k16*16;  byte ^= (row & 7) << 4;
        s16x8 val = {0,0,0,0,0,0,0,0};
        int grow = row0 + row;
        if (grow < N_NODES) val = *(const s16x8*)(x1b + (size_t)grow*128 + k16*8);
        *(s16x8*)(sA + byte) = val;
    }
    __syncthreads();

    int w = threadIdx.x >> 6, l = threadIdx.x & 63;

    // ---- GEMM1: mid = leaky(x1 @ W1 + b1); wave w -> cols w*64..+63
    {
        int n0 = w*64;
        f32x4 acc[4][4];
        #pragma unroll
        for (int rf=0;rf<4;++rf)
            #pragma unroll
            for (int cf=0;cf<4;++cf) acc[rf][cf] = (f32x4){0.f,0.f,0.f,0.f};
        s16x8 af[2][4], bfr[2][4];
        #pragma unroll
        for (int rf=0;rf<4;++rf){
            int row = rf*16 + (l & 15);
            int byte = row*256 + (l >> 4)*16;  byte ^= (row & 7) << 4;
            af[0][rf] = *(const s16x8*)(sA + byte);
        }
        #pragma unroll
        for (int cf=0;cf<4;++cf){
            int n = n0 + cf*16 + (l & 15);
            bfr[0][cf] = *(const s16x8*)(w1T + (size_t)n*128 + (l >> 4)*8);
        }
        #pragma unroll
        for (int kb = 0; kb < 4; ++kb){
            int cur = kb & 1, nxt = cur ^ 1;
            if (kb < 3){
                #pragma unroll
                for (int rf=0;rf<4;++rf){
                    int row = rf*16 + (l & 15);
                    int byte = row*256 + (kb+1)*64 + (l >> 4)*16;  byte ^= (row & 7) << 4;
                    af[nxt][rf] = *(const s16x8*)(sA + byte);
                }
                #pragma unroll
                for (int cf=0;cf<4;++cf){
                    int n = n0 + cf*16 + (l & 15);
                    bfr[nxt][cf] = *(const s16x8*)(w1T + (size_t)n*128 + (kb+1)*32 + (l >> 4)*8);
                }
            }
            #pragma unroll
            for (int rf=0;rf<4;++rf)
                #pragma unroll
                for (int cf=0;cf<4;++cf)
                    acc[rf][cf] = __builtin_amdgcn_mfma_f32_16x16x32_bf16(af[cur][rf], bfr[cur][cf], acc[rf][cf], 0, 0, 0);
        }
        #pragma unroll
        for (int cf=0;cf<4;++cf){
            int col = n0 + cf*16 + (l & 15);
            float bb = b1[col];
            #pragma unroll
            for (int rf=0;rf<4;++rf){
                #pragma unroll
                for (int r=0;r<4;++r){
                    int row = rf*16 + ((l >> 4) << 2) + r;
                    float val = leaky(acc[rf][cf][r] + bb);
                    int byte = row*512 + col*2;  byte ^= (row & 7) << 4;
                    *(unsigned short*)(sMid + byte) = f2bf(val);
                }
            }
        }
    }
    __syncthreads();

    // ---- GEMM2: ff = mid @ W2; wave w -> cols w*32..+31; K=256
    f32x4 acc2[2][4];
    {
        int n0 = w*32;
        #pragma unroll
        for (int cf=0;cf<2;++cf)
            #pragma unroll
            for (int rf=0;rf<4;++rf) acc2[cf][rf] = (f32x4){0.f,0.f,0.f,0.f};
        s16x8 af[2][4], bfr[2][2];
        #pragma unroll
        for (int rf=0;rf<4;++rf){
            int row = rf*16 + (l & 15);
            int byte = row*512 + (l >> 4)*16;  byte ^= (row & 7) << 4;
            af[0][rf] = *(const s16x8*)(sMid + byte);
        }
        #pragma unroll
        for (int cf=0;cf<2;++cf){
            int n = n0 + cf*16 + (l & 15);
            bfr[0][cf] = *(const s16x8*)(w2T + (size_t)n*256 + (l >> 4)*8);
        }
        #pragma unroll
        for (int kb = 0; kb < 8; ++kb){
            int cur = kb & 1, nxt = cur ^ 1;
            if (kb < 7){
                #pragma unroll
                for (int rf=0;rf<4;++rf){
                    int row = rf*16 + (l & 15);
                    int byte = row*512 + (kb+1)*64 + (l >> 4)*16;  byte ^= (row & 7) << 4;
                    af[nxt][rf] = *(const s16x8*)(sMid + byte);
                }
                #pragma unroll
                for (int cf=0;cf<2;++cf){
                    int n = n0 + cf*16 + (l & 15);
                    bfr[nxt][cf] = *(const s16x8*)(w2T + (size_t)n*256 + (kb+1)*32 + (l >> 4)*8);
                }
            }
            #pragma unroll
            for (int cf=0;cf<2;++cf)
                #pragma unroll
                for (int rf=0;rf<4;++rf)
                    acc2[cf][rf] = __builtin_amdgcn_mfma_f32_16x16x32_bf16(af[cur][rf], bfr[cur][cf], acc2[cf][rf], 0, 0, 0);
        }
    }
    __syncthreads();   // all GEMM2 reads of sMid done; reuse as ffout f32

    float* sFF = (float*)sMid;
    {
        int n0 = w*32;
        #pragma unroll
        for (int cf=0;cf<2;++cf){
            int col = n0 + cf*16 + (l & 15);
            float bb = b2[col];
            #pragma unroll
            for (int rf=0;rf<4;++rf){
                #pragma unroll
                for (int r=0;r<4;++r){
                    int row = rf*16 + ((l >> 4) << 2) + r;
                    int byte = row*512 + col*4;  byte ^= (row & 7) << 4;
                    *(float*)((char*)sFF + byte) = acc2[cf][rf][r] + bb;
                }
            }
        }
    }
    __syncthreads();

    // ---- LN chain: c = LN2(x1+ff), hn = LN3(c), act(if !last), h = hn + h_in
    int d0 = l*2;
    float g2a = n2g[d0], g2b = n2g[d0+1], be2a = n2b[d0], be2b = n2b[d0+1];
    float gla = lng[d0], glb = lng[d0+1], bla = lnb[d0], blb = lnb[d0+1];
    for (int i = 0; i < 16; ++i){
        int rr = w*16 + i;
        int grow = row0 + rr;
        if (grow >= N_NODES) break;
        int byte = rr*512 + d0*4;  byte ^= (rr & 7) << 4;
        float2 ff = *(float2*)((char*)sFF + byte);
        int byteA = rr*256 + d0*2;  byteA ^= (rr & 7) << 4;
        unsigned int xu = *(unsigned int*)(sA + byteA);   // x1 residual from LDS bf16
        unsigned int hu = *(const unsigned int*)(hbin + (size_t)grow*DIM + d0);
        float t0 = bflo(xu) + ff.x, t1 = bfhi(xu) + ff.y;
        float sum = t0 + t1, ss = t0*t0 + t1*t1;
        #pragma unroll
        for (int off = 1; off < 64; off <<= 1){
            sum += __shfl_xor(sum, off);
            ss  += __shfl_xor(ss,  off);
        }
        float mu = sum*(1.f/DIM);
        float rstd = rsqrtf(ss*(1.f/DIM) - mu*mu + LN_EPS);
        float c0 = (t0-mu)*rstd*g2a + be2a;
        float c1 = (t1-mu)*rstd*g2b + be2b;
        float sum2 = c0 + c1, ss2 = c0*c0 + c1*c1;
        #pragma unroll
        for (int off = 1; off < 64; off <<= 1){
            sum2 += __shfl_xor(sum2, off);
            ss2  += __shfl_xor(ss2,  off);
        }
        float mu2 = sum2*(1.f/DIM);
        float rstd2 = rsqrtf(ss2*(1.f/DIM) - mu2*mu2 + LN_EPS);
        float z0 = (c0-mu2)*rstd2*gla + bla;
        float z1 = (c1-mu2)*rstd2*glb + blb;
        if (!last){ z0 = leaky(z0); z1 = leaky(z1); }
        float o0 = z0 + bflo(hu), o1 = z1 + bfhi(hu);
        if (last){
            *(float2*)(h + (size_t)grow*DIM + d0) = make_float2(o0, o1);
        } else {
            unsigned int pk = (unsigned int)f2bf(o0) | ((unsigned int)f2bf(o1) << 16);
            *(unsigned int*)(hb + (size_t)grow*DIM + d0) = pk;
        }
    }
}

extern "C" void kernel_launch(void* const* d_in, const int* in_sizes, int n_in,
                              void* d_out, int out_size, void* d_ws, size_t ws_size,
                              hipStream_t stream)
{
    const int*   edge_index = (const int*)  d_in[1];
    const float* edge_attr  = (const float*)d_in[2];
    const float* node_table = (const float*)d_in[3];
    const float* Wee = (const float*)d_in[4];
    const float* bee = (const float*)d_in[5];
    const float* Wq  = (const float*)d_in[6];  const float* bq = (const float*)d_in[7];
    const float* Wk  = (const float*)d_in[8];  const float* bk = (const float*)d_in[9];
    const float* Wv  = (const float*)d_in[10]; const float* bv = (const float*)d_in[11];
    const float* We  = (const float*)d_in[12]; const float* be = (const float*)d_in[13];
    const float* Ws  = (const float*)d_in[14]; const float* bs = (const float*)d_in[15];
    const float* W1  = (const float*)d_in[16]; const float* b1 = (const float*)d_in[17];
    const float* W2  = (const float*)d_in[18]; const float* b2 = (const float*)d_in[19];
    const float* n1g = (const float*)d_in[20]; const float* n1b = (const float*)d_in[21];
    const float* n2g = (const float*)d_in[22]; const float* n2b = (const float*)d_in[23];
    const float* lng = (const float*)d_in[24]; const float* lnb = (const float*)d_in[25];

    float* h = (float*)d_out;

    char* ws = (char*)d_ws;
    size_t off = 0;
    auto alloc = [&](size_t bytes)->void*{
        void* p = ws + off;
        off += (bytes + 255) & ~(size_t)255;
        return p;
    };
    unsigned int*   qs   = (unsigned int*)  alloc(sizeof(int)*(size_t)N_NODES*DIM);
    unsigned int*   kv   = (unsigned int*)  alloc(sizeof(int)*(size_t)N_NODES*DIM);
    unsigned short* hb   = (unsigned short*)alloc(sizeof(short)*(size_t)N_NODES*DIM);
    unsigned short* x1b  = (unsigned short*)alloc(sizeof(short)*(size_t)N_NODES*DIM);
    unsigned int*   eab  = (unsigned int*)  alloc(sizeof(int)*(size_t)N_EDGES*4);
    unsigned short* wqkvsT = (unsigned short*)alloc(sizeof(short)*NLAYER*512*128);
    unsigned short* w1T    = (unsigned short*)alloc(sizeof(short)*NLAYER*256*128);
    unsigned short* w2T    = (unsigned short*)alloc(sizeof(short)*NLAYER*128*256);
    float* weff = (float*)alloc(sizeof(float)*NLAYER*8*DIM);
    int* rowptr = (int*)alloc(sizeof(int)*(N_NODES+1));
    int* cnt    = (int*)alloc(sizeof(int)*N_NODES);
    int* fill   = (int*)alloc(sizeof(int)*N_NODES);
    int* srcs   = (int*)alloc(sizeof(int)*N_EDGES);

    const int* srcIdx = edge_index;
    const int* dstIdx = edge_index + N_EDGES;

    init_h_kernel<<<(N_NODES*DIM+255)/256, 256, 0, stream>>>(node_table, hb);
    zero2_kernel<<<(N_NODES+255)/256, 256, 0, stream>>>(cnt, fill);
    count_kernel<<<(N_EDGES+255)/256, 256, 0, stream>>>(dstIdx, cnt);
    scan_kernel<<<1, 1024, 0, stream>>>(cnt, rowptr);
    scatter_kernel<<<(N_EDGES+255)/256, 256, 0, stream>>>(srcIdx, dstIdx, edge_attr,
                                                          rowptr, fill, srcs, eab);
    prepw_kernel<<<(NLAYER*131072+255)/256, 256, 0, stream>>>(Wq, Wk, Wv, Ws, W1, W2,
                                                              wqkvsT, w1T, w2T);
    weff_all_kernel<<<NLAYER, 128, 0, stream>>>(Wee, bee, We, be, weff);

    int tiles = (N_NODES + 63)/64;
    for (int l = 0; l < NLAYER; ++l){
        qkvs_mfma_kernel<<<dim3(tiles, 2), 256, 0, stream>>>(hb,
            wqkvsT + (size_t)l*65536,
            bq + (size_t)l*DIM, bk + (size_t)l*DIM, bv + (size_t)l*DIM, bs + (size_t)l*DIM,
            qs, kv);
        attn_kernel<<<(N_NODES+7)/8, 256, 0, stream>>>(qs, kv,
            weff + (size_t)l*8*DIM, rowptr, srcs, eab, hb,
            n1g + (size_t)l*DIM, n1b + (size_t)l*DIM, x1b);
        ffn_mfma_kernel<<<tiles, 256, 0, stream>>>(x1b, hb,
            w1T + (size_t)l*32768, b1 + (size_t)l*2*DIM,
            w2T + (size_t)l*32768, b2 + (size_t)l*DIM,
            n2g + (size_t)l*DIM, n2b + (size_t)l*DIM,
            lng + (size_t)l*DIM, lnb + (size_t)l*DIM,
            (l == NLAYER-1) ? 1 : 0, h, hb);
    }
}